// Round 6
// baseline (224.219 us; speedup 1.0000x reference)
//
#include <hip/hip_runtime.h>

#define EPS   1e-5f
#define SLOPE 0.01f

// ---------------------------------------------------------------------------
// Workspace layout (float offsets). Total 20,287,424 floats = 81.1 MB.
// ---------------------------------------------------------------------------
#define WS_H1B  0L            // h1  bf16 NHWC (64,56,56,96)   (9633792 f)
#define WS_OFF  9633792L      // off f32 [n=12544][32]            401408
#define WS_S1   10035200L     // bn1 scale f32 [96]
#define WS_T1   10035296L     // bn1 bias  f32 [96]
#define WS_T2   10035392L     // fused dcn_b+bn2 bias f32 [768]
#define WS_SB   10036160L     // S   bf16 [n=12544][k=1536]    (9633792 f)
#define WS_WTB  19669952L     // Wtb bf16 [oc=768][k=1536]      (589824 f)
#define WS_WOB  20259776L     // Wob bf16 [oc=32][k=1536]        (24576 f)
#define WS_W1B  20284352L     // W1b bf16 [ks=2][oc=96][kl=32]    (3072 f)

__device__ __forceinline__ unsigned short f2bf(float f) {
    unsigned int u = __builtin_bit_cast(unsigned int, f);
    u += 0x7fffu + ((u >> 16) & 1u);
    return (unsigned short)(u >> 16);
}
__device__ __forceinline__ float bf2f(unsigned short u) {
    unsigned int t = ((unsigned int)u) << 16;
    return __builtin_bit_cast(float, t);
}

typedef __attribute__((ext_vector_type(4))) unsigned short ushort4v;
typedef __attribute__((ext_vector_type(8))) unsigned short ushort8v;
typedef __attribute__((ext_vector_type(8))) short bf16x8;
typedef __attribute__((ext_vector_type(4))) float floatx4;

// ---------------------------------------------------------------------------
// K0: weight prep, transpose-via-LDS for coalescing.
//   blk <  768 : Wtb[oc][k] = bf16(dcn_w[oc][c][kk] * inv2[oc]), k = kk*96+c
//   blk <  800 : Wob[oc][k] = bf16(off_w[oc][c][khw]),           k = khw*96+c
//   blk == 800 : W1b (stem weights, padded K 48->64) + s1/t1/t2
// ---------------------------------------------------------------------------
__global__ __launch_bounds__(256) void k0_prep(
    const float* __restrict__ stem_w, const float* __restrict__ stem_b,
    const float* __restrict__ bn1_g,  const float* __restrict__ bn1_b,
    const float* __restrict__ bn1_m,  const float* __restrict__ bn1_v,
    const float* __restrict__ off_w,  const float* __restrict__ dcn_w,
    const float* __restrict__ dcn_b,  const float* __restrict__ bn2_g,
    const float* __restrict__ bn2_b,  const float* __restrict__ bn2_m,
    const float* __restrict__ bn2_v,  float* __restrict__ ws)
{
    const int tid = threadIdx.x;
    const int blk = blockIdx.x;
    unsigned short* Wtb = (unsigned short*)(ws + WS_WTB);
    unsigned short* Wob = (unsigned short*)(ws + WS_WOB);
    unsigned short* W1b = (unsigned short*)(ws + WS_W1B);

    if (blk < 800) {
        __shared__ float row[1536];
        const int oc = (blk < 768) ? blk : blk - 768;
        const float* src = (blk < 768) ? (dcn_w + (long)oc * 1536)
                                       : (off_w + (long)oc * 1536);
        for (int i = tid; i < 1536; i += 256) row[i] = src[i];
        float sc = 1.f;
        if (blk < 768) sc = bn2_g[oc] * rsqrtf(bn2_v[oc] + EPS);
        __syncthreads();
        if (tid < 192) {
            int k0 = tid * 8;
            ushort8v o;
#pragma unroll
            for (int t = 0; t < 8; t++) {
                int k = k0 + t;
                int kk = k / 96, c = k % 96;      // k = kk*96 + c
                ((unsigned short*)&o)[t] = f2bf(row[c * 16 + kk] * sc);
            }
            unsigned short* dst = (blk < 768) ? (Wtb + (long)oc * 1536 + k0)
                                              : (Wob + (long)oc * 1536 + k0);
            *(ushort8v*)dst = o;
        }
    } else {
        // W1b: [ks=2][oc=96][kl=32], k = ks*32+kl, zero-pad k>=48
        for (int i = tid; i < 6144; i += 256) {
            int ks = i / 3072, rr = i % 3072;
            int oc = rr >> 5, kl = rr & 31;
            int k = ks * 32 + kl;
            W1b[i] = f2bf(k < 48 ? stem_w[oc * 48 + k] : 0.f);
        }
        if (tid < 96) {
            float s = bn1_g[tid] * rsqrtf(bn1_v[tid] + EPS);
            ws[WS_S1 + tid] = s;
            ws[WS_T1 + tid] = stem_b[tid] * s + bn1_b[tid] - bn1_m[tid] * s;
        }
        for (int i = tid; i < 768; i += 256) {
            float inv2 = bn2_g[i] * rsqrtf(bn2_v[i] + EPS);
            ws[WS_T2 + i] = dcn_b[i] * inv2 + bn2_b[i] - bn2_m[i] * inv2;
        }
    }
}

// ---------------------------------------------------------------------------
// K1: stem conv as bf16 MFMA GEMM, coalesced staging + LDS-repacked stores.
// h1[p][c] = im2col(x)[p][k] * W1b[c][k]^T. N=200704, M=96, K=48 (pad 64).
// ---------------------------------------------------------------------------
__global__ __launch_bounds__(256) void k1_stem_mfma(
    const float* __restrict__ x, const unsigned short* __restrict__ W1b,
    const float* __restrict__ s1, const float* __restrict__ t1,
    unsigned short* __restrict__ h1)
{
    const int tid  = threadIdx.x;
    const int wave = tid >> 6, lane = tid & 63;
    const int m = lane & 15, quad = lane >> 4;
    const int p0 = blockIdx.x * 128;

    __shared__ unsigned short sm[14336];   // 28672 B
    unsigned short* sA = sm;               // [2][128][32] : ks*4096 + r*32 + kl
    unsigned short* sB = sm + 8192;        // [2][96][32]  : ks*3072 + oc*32 + kl

    // stage B: 12288 B contiguous via 12 x 1024 B global_load_lds
#pragma unroll
    for (int i = 0; i < 3; i++) {
        int inst = wave * 3 + i;
        const unsigned short* g = W1b + inst * 512 + lane * 8;
        __builtin_amdgcn_global_load_lds(
            (const __attribute__((address_space(1))) void*)g,
            (__attribute__((address_space(3))) void*)(sB + inst * 512), 16, 0, 0);
    }

    // zero pad region sA[1][*][16..31]
    {
        int r = tid >> 1, off = 16 + (tid & 1) * 8;
        *(ushort8v*)&sA[4096 + r * 32 + off] = (ushort8v)0;
    }

    // stage A coalesced: unit = i*256+tid; r = unit&127 (consecutive lanes ->
    // consecutive pixels -> contiguous 16B chunks of one x row), s = unit>>7.
#pragma unroll
    for (int i = 0; i < 6; i++) {
        int unit = i * 256 + tid;
        int r = unit & 127, s = unit >> 7;
        int ci = s >> 2, kh = s & 3;
        int p = p0 + r;
        int b = p / 3136, rem = p % 3136;
        int oy = rem / 56, ox = rem % 56;
        float4 v = *(const float4*)&x[((long)((b * 3 + ci) * 224 + oy * 4 + kh)) * 224 + ox * 4];
        ushort4v hv;
        hv.x = f2bf(v.x); hv.y = f2bf(v.y); hv.z = f2bf(v.z); hv.w = f2bf(v.w);
        int k0i = ci * 16 + kh * 4;
        *(ushort4v*)&sA[(k0i >> 5) * 4096 + r * 32 + (k0i & 31)] = hv;
    }
    __syncthreads();

    bf16x8 bfv[6][2], af[2][2];
#pragma unroll
    for (int j = 0; j < 6; j++)
#pragma unroll
        for (int ks = 0; ks < 2; ks++)
            bfv[j][ks] = *(const bf16x8*)&sB[ks * 3072 + (j * 16 + m) * 32 + quad * 8];
#pragma unroll
    for (int rt = 0; rt < 2; rt++)
#pragma unroll
        for (int ks = 0; ks < 2; ks++)
            af[rt][ks] = *(const bf16x8*)&sA[ks * 4096 + (wave * 32 + rt * 16 + m) * 32 + quad * 8];

    floatx4 acc[2][6];
#pragma unroll
    for (int rt = 0; rt < 2; rt++)
#pragma unroll
        for (int j = 0; j < 6; j++) {
            floatx4 a = (floatx4)0.f;
            a = __builtin_amdgcn_mfma_f32_16x16x32_bf16(af[rt][0], bfv[j][0], a, 0, 0, 0);
            a = __builtin_amdgcn_mfma_f32_16x16x32_bf16(af[rt][1], bfv[j][1], a, 0, 0, 0);
            acc[rt][j] = a;
        }

    __syncthreads();   // done reading sA/sB; reuse sm as [128][96] repack buf
#pragma unroll
    for (int j = 0; j < 6; j++) {
        int c = j * 16 + m;
        float sc = s1[c], bi = t1[c];
#pragma unroll
        for (int rt = 0; rt < 2; rt++)
#pragma unroll
            for (int r = 0; r < 4; r++) {
                int row = wave * 32 + rt * 16 + quad * 4 + r;
                float v = acc[rt][j][r] * sc + bi;
                v = v >= 0.f ? v : SLOPE * v;
                sm[row * 96 + c] = f2bf(v);
            }
    }
    __syncthreads();
    // coalesced copy-out: 12288 ushorts, 6 x ushort8 per thread
#pragma unroll
    for (int i = 0; i < 6; i++) {
        int idx = (i * 256 + tid) * 8;
        *(ushort8v*)&h1[(long)p0 * 96 + idx] = *(const ushort8v*)&sm[idx];
    }
}

// ---------------------------------------------------------------------------
// K2: offset conv as bf16 MFMA GEMM reading im2col rows DIRECTLY from h1.
// off[n][oc] = im2col(h1)[n][k] * Wob[oc][k]^T.  N=12544, M=32, K=1536.
// ---------------------------------------------------------------------------
__global__ __launch_bounds__(256) void k2_mfma(
    const unsigned short* __restrict__ h1,   // bf16 NHWC
    const unsigned short* __restrict__ Wob,  // [32][1536] bf16
    const float* __restrict__ off_b, float* __restrict__ off)
{
    const int tid  = threadIdx.x;
    const int wave = tid >> 6;
    const int lane = tid & 63;
    const int n0   = blockIdx.x * 128;
    const int m    = lane & 15;
    const int quad = lane >> 4;

    __shared__ unsigned short sA[128 * 32];
    __shared__ unsigned short sB[32 * 32];

    const int skoff = (lane & 3) * 8;
    int n_a = n0 + wave * 32 + (lane >> 2);
    int n_b = n_a + 16;
    int ba = n_a / 196, pa = n_a % 196;
    int bb = n_b / 196, pb = n_b % 196;
    long pixa = ((long)(ba * 56 + (pa / 14) * 4) * 56 + (pa % 14) * 4);
    long pixb = ((long)(bb * 56 + (pb / 14) * 4) * 56 + (pb % 14) * 4);

    const unsigned short* gB = Wob + (long)((wave & 1) * 16 + (lane >> 2)) * 1536 + skoff;
    unsigned short* lA0 = &sA[(wave * 32 +  0) * 32];
    unsigned short* lA1 = &sA[(wave * 32 + 16) * 32];
    unsigned short* lB  = &sB[((wave & 1) * 16) * 32];

    floatx4 acc[2][2];
#pragma unroll
    for (int i = 0; i < 2; i++)
#pragma unroll
        for (int j = 0; j < 2; j++) acc[i][j] = (floatx4)0.f;

    for (int kt = 0; kt < 48; ++kt) {
        int khw = kt / 3;
        int c0  = (kt - khw * 3) * 32;
        int kh  = khw >> 2, kw = khw & 3;
        long eoff = (long)(kh * 56 + kw) * 96 + c0 + skoff;
        const unsigned short* gA0 = h1 + pixa * 96 + eoff;
        const unsigned short* gA1 = h1 + pixb * 96 + eoff;

        __syncthreads();
        __builtin_amdgcn_global_load_lds(
            (const __attribute__((address_space(1))) void*)gA0,
            (__attribute__((address_space(3))) void*)lA0, 16, 0, 0);
        __builtin_amdgcn_global_load_lds(
            (const __attribute__((address_space(1))) void*)gA1,
            (__attribute__((address_space(3))) void*)lA1, 16, 0, 0);
        if (wave < 2)
            __builtin_amdgcn_global_load_lds(
                (const __attribute__((address_space(1))) void*)gB,
                (__attribute__((address_space(3))) void*)lB, 16, 0, 0);
        gB += 32;
        __syncthreads();

        bf16x8 af[2], bfr[2];
#pragma unroll
        for (int i = 0; i < 2; i++)
            af[i] = *(const bf16x8*)&sA[(wave * 32 + i * 16 + m) * 32 + quad * 8];
#pragma unroll
        for (int j = 0; j < 2; j++)
            bfr[j] = *(const bf16x8*)&sB[(j * 16 + m) * 32 + quad * 8];
#pragma unroll
        for (int i = 0; i < 2; i++)
#pragma unroll
            for (int j = 0; j < 2; j++)
                acc[i][j] = __builtin_amdgcn_mfma_f32_16x16x32_bf16(
                    af[i], bfr[j], acc[i][j], 0, 0, 0);
    }

    float tb[2];
#pragma unroll
    for (int j = 0; j < 2; j++) tb[j] = off_b[j * 16 + m];
#pragma unroll
    for (int i = 0; i < 2; i++)
#pragma unroll
        for (int r = 0; r < 4; r++) {
            long n = n0 + wave * 32 + i * 16 + quad * 4 + r;
#pragma unroll
            for (int j = 0; j < 2; j++)
                off[n * 32 + j * 16 + m] = acc[i][j][r] + tb[j];
        }
}

// ---------------------------------------------------------------------------
// K3: bilinear sampling from bf16 h1 -> S bf16 [n][k], k = kk*96 + c.
// ---------------------------------------------------------------------------
__global__ __launch_bounds__(384) void k3_sample(
    const unsigned short* __restrict__ h1, const float* __restrict__ off,
    unsigned short* __restrict__ S)
{
    const int p = blockIdx.x;     // 0..195
    const int b = blockIdx.y;     // 0..63
    const int y = p / 14, xo = p % 14;
    const int tid = threadIdx.x;
    const int c4 = tid % 24, kk = tid / 24;
    const int kh = kk >> 2, kw = kk & 3;

    const float* ob = off + ((long)(b * 196 + p)) * 32;
    float dy = ob[kk * 2];
    float dx = ob[kk * 2 + 1];

    float py = (float)(y * 4 + kh) + dy;
    float px = (float)(xo * 4 + kw) + dx;
    float y0f = floorf(py), x0f = floorf(px);
    float wy = py - y0f, wx = px - x0f;
    int y0 = (int)y0f, x0 = (int)x0f;
    int y1 = y0 + 1,  x1 = x0 + 1;

    float my0 = (y0 >= 0 && y0 < 56) ? 1.f : 0.f;
    float my1 = (y1 >= 0 && y1 < 56) ? 1.f : 0.f;
    float mx0 = (x0 >= 0 && x0 < 56) ? 1.f : 0.f;
    float mx1 = (x1 >= 0 && x1 < 56) ? 1.f : 0.f;
    int y0c = min(max(y0, 0), 55), y1c = min(max(y1, 0), 55);
    int x0c = min(max(x0, 0), 55), x1c = min(max(x1, 0), 55);

    const unsigned short* hb = h1 + (long)b * 56 * 56 * 96 + c4 * 4;
    ushort4v v00 = *(const ushort4v*)&hb[(y0c * 56 + x0c) * 96];
    ushort4v v01 = *(const ushort4v*)&hb[(y0c * 56 + x1c) * 96];
    ushort4v v10 = *(const ushort4v*)&hb[(y1c * 56 + x0c) * 96];
    ushort4v v11 = *(const ushort4v*)&hb[(y1c * 56 + x1c) * 96];

    float w00 = my0 * mx0 * (1.f - wy) * (1.f - wx);
    float w01 = my0 * mx1 * (1.f - wy) * wx;
    float w10 = my1 * mx0 * wy * (1.f - wx);
    float w11 = my1 * mx1 * wy * wx;

    ushort4v rr;
#pragma unroll
    for (int c = 0; c < 4; c++) {
        float v = bf2f(((unsigned short*)&v00)[c]) * w00
                + bf2f(((unsigned short*)&v01)[c]) * w01
                + bf2f(((unsigned short*)&v10)[c]) * w10
                + bf2f(((unsigned short*)&v11)[c]) * w11;
        ((unsigned short*)&rr)[c] = f2bf(v);
    }

    long n = (long)b * 196 + p;
    *(ushort4v*)&S[n * 1536 + kk * 96 + c4 * 4] = rr;
}

// ---------------------------------------------------------------------------
// K4: bf16 MFMA GEMM  C[n][oc] = S[n][k] * Wtb[oc][k]^T  (N=12544,M=768,K=1536)
// 128x128 tile. Per iteration: TWO BK=32 stages (32 MFMA per barrier drain),
// 24 iterations. XCD-grouping swizzle: all 6 oc-tiles of an n-tile run
// consecutively on one XCD (lid%8 round-robin heuristic) so S-tile re-reads
// hit that XCD's 4MB L2. Epilogue: leaky(acc + t2[oc]) -> out.
// ---------------------------------------------------------------------------
__global__ __launch_bounds__(256) void k4_gemm_mfma(
    const unsigned short* __restrict__ S,    // [12544][1536] bf16
    const unsigned short* __restrict__ Wtb,  // [768][1536]  bf16 (B^T, scaled)
    const float* __restrict__ t2, float* __restrict__ out)
{
    const int tid  = threadIdx.x;
    const int wave = tid >> 6;
    const int lane = tid & 63;

    // bijective swizzle 0..587: XCDs 0-3 get 74 works, 4-7 get 73
    int lid = blockIdx.x + blockIdx.y * 6;
    int xcd = lid & 7, s = lid >> 3;
    int work = (xcd < 4) ? (xcd * 74 + s) : (296 + (xcd - 4) * 73 + s);
    const int oc0 = (work % 6) * 128;
    const int n0  = (work / 6) * 128;

    const int wr  = wave >> 1, wc = wave & 1;
    const int m    = lane & 15;
    const int quad = lane >> 4;

    __shared__ unsigned short sA[2][128 * 32];
    __shared__ unsigned short sB[2][128 * 32];

    const int srow  = wave * 32 + (lane >> 2);
    const int skoff = (lane & 3) * 8;
    const unsigned short* gA0 = S   + (long)(n0  + srow) * 1536 + skoff;
    const unsigned short* gA1 = gA0 + 16L * 1536;
    const unsigned short* gB0 = Wtb + (long)(oc0 + srow) * 1536 + skoff;
    const unsigned short* gB1 = gB0 + 16L * 1536;
    unsigned short* lA0 = &sA[0][(wave * 32 +  0) * 32];
    unsigned short* lA1 = &sA[0][(wave * 32 + 16) * 32];
    unsigned short* lB0 = &sB[0][(wave * 32 +  0) * 32];
    unsigned short* lB1 = &sB[0][(wave * 32 + 16) * 32];
    const int bufstride = 128 * 32;   // ushorts between buf0 and buf1

    floatx4 acc[4][4];
#pragma unroll
    for (int i = 0; i < 4; i++)
#pragma unroll
        for (int j = 0; j < 4; j++) acc[i][j] = (floatx4)0.f;

    for (int kt = 0; kt < 24; ++kt) {
        __syncthreads();
        // buffer 0: k chunk kt*64 .. +32
        __builtin_amdgcn_global_load_lds(
            (const __attribute__((address_space(1))) void*)gA0,
            (__attribute__((address_space(3))) void*)lA0, 16, 0, 0);
        __builtin_amdgcn_global_load_lds(
            (const __attribute__((address_space(1))) void*)gA1,
            (__attribute__((address_space(3))) void*)lA1, 16, 0, 0);
        __builtin_amdgcn_global_load_lds(
            (const __attribute__((address_space(1))) void*)gB0,
            (__attribute__((address_space(3))) void*)lB0, 16, 0, 0);
        __builtin_amdgcn_global_load_lds(
            (const __attribute__((address_space(1))) void*)gB1,
            (__attribute__((address_space(3))) void*)lB1, 16, 0, 0);
        // buffer 1: k chunk kt*64+32 .. +64
        __builtin_amdgcn_global_load_lds(
            (const __attribute__((address_space(1))) void*)(gA0 + 32),
            (__attribute__((address_space(3))) void*)(lA0 + bufstride), 16, 0, 0);
        __builtin_amdgcn_global_load_lds(
            (const __attribute__((address_space(1))) void*)(gA1 + 32),
            (__attribute__((address_space(3))) void*)(lA1 + bufstride), 16, 0, 0);
        __builtin_amdgcn_global_load_lds(
            (const __attribute__((address_space(1))) void*)(gB0 + 32),
            (__attribute__((address_space(3))) void*)(lB0 + bufstride), 16, 0, 0);
        __builtin_amdgcn_global_load_lds(
            (const __attribute__((address_space(1))) void*)(gB1 + 32),
            (__attribute__((address_space(3))) void*)(lB1 + bufstride), 16, 0, 0);
        gA0 += 64; gA1 += 64; gB0 += 64; gB1 += 64;
        __syncthreads();

#pragma unroll
        for (int h = 0; h < 2; h++) {
            bf16x8 af[4], bf[4];
#pragma unroll
            for (int i = 0; i < 4; i++)
                af[i] = *(const bf16x8*)&sA[h][(wr * 64 + i * 16 + m) * 32 + quad * 8];
#pragma unroll
            for (int j = 0; j < 4; j++)
                bf[j] = *(const bf16x8*)&sB[h][(wc * 64 + j * 16 + m) * 32 + quad * 8];
#pragma unroll
            for (int i = 0; i < 4; i++)
#pragma unroll
                for (int j = 0; j < 4; j++)
                    acc[i][j] = __builtin_amdgcn_mfma_f32_16x16x32_bf16(
                        af[i], bf[j], acc[i][j], 0, 0, 0);
        }
    }

    float tb[4];
#pragma unroll
    for (int j = 0; j < 4; j++) tb[j] = t2[oc0 + wc * 64 + j * 16 + m];
#pragma unroll
    for (int i = 0; i < 4; i++) {
#pragma unroll
        for (int r = 0; r < 4; r++) {
            long n = n0 + wr * 64 + i * 16 + quad * 4 + r;
            float* orow = out + n * 768 + oc0 + wc * 64 + m;
#pragma unroll
            for (int j = 0; j < 4; j++) {
                float v = acc[i][j][r] + tb[j];
                orow[j * 16] = v >= 0.f ? v : SLOPE * v;
            }
        }
    }
}

// ---------------------------------------------------------------------------
extern "C" void kernel_launch(void* const* d_in, const int* in_sizes, int n_in,
                              void* d_out, int out_size, void* d_ws, size_t ws_size,
                              hipStream_t stream)
{
    const float* x      = (const float*)d_in[0];
    const float* stem_w = (const float*)d_in[1];
    const float* stem_b = (const float*)d_in[2];
    const float* bn1_g  = (const float*)d_in[3];
    const float* bn1_b  = (const float*)d_in[4];
    const float* bn1_m  = (const float*)d_in[5];
    const float* bn1_v  = (const float*)d_in[6];
    const float* off_w  = (const float*)d_in[7];
    const float* off_b  = (const float*)d_in[8];
    const float* dcn_w  = (const float*)d_in[9];
    const float* dcn_b  = (const float*)d_in[10];
    const float* bn2_g  = (const float*)d_in[11];
    const float* bn2_b  = (const float*)d_in[12];
    const float* bn2_m  = (const float*)d_in[13];
    const float* bn2_v  = (const float*)d_in[14];

    float* ws  = (float*)d_ws;        // needs 81.2 MB
    float* out = (float*)d_out;

    unsigned short* h1  = (unsigned short*)(ws + WS_H1B);
    float* off = ws + WS_OFF;
    float* s1  = ws + WS_S1;
    float* t1  = ws + WS_T1;
    float* t2  = ws + WS_T2;
    unsigned short* Sb  = (unsigned short*)(ws + WS_SB);
    unsigned short* Wtb = (unsigned short*)(ws + WS_WTB);
    unsigned short* Wob = (unsigned short*)(ws + WS_WOB);
    unsigned short* W1b = (unsigned short*)(ws + WS_W1B);

    k0_prep<<<801, 256, 0, stream>>>(stem_w, stem_b, bn1_g, bn1_b, bn1_m, bn1_v,
                                     off_w, dcn_w, dcn_b, bn2_g, bn2_b, bn2_m,
                                     bn2_v, ws);
    k1_stem_mfma<<<1568, 256, 0, stream>>>(x, W1b, s1, t1, h1);
    k2_mfma<<<98, 256, 0, stream>>>(h1, Wob, off_b, off);
    k3_sample<<<dim3(196, 64), 384, 0, stream>>>(h1, off, Sb);
    k4_gemm_mfma<<<dim3(6, 98), 256, 0, stream>>>(Sb, Wtb, t2, out);
}

// Round 7
// 216.459 us; speedup vs baseline: 1.0359x; 1.0359x over previous
//
#include <hip/hip_runtime.h>

#define EPS   1e-5f
#define SLOPE 0.01f

// ---------------------------------------------------------------------------
// Workspace layout (float offsets). Total 20,287,424 floats = 81.1 MB.
// ---------------------------------------------------------------------------
#define WS_H1B  0L            // h1  bf16 NHWC (64,56,56,96)   (9633792 f)
#define WS_OFF  9633792L      // off f32 [n=12544][32]            401408
#define WS_S1   10035200L     // bn1 scale f32 [96]
#define WS_T1   10035296L     // bn1 bias  f32 [96]
#define WS_T2   10035392L     // fused dcn_b+bn2 bias f32 [768]
#define WS_SB   10036160L     // S   bf16 [n=12544][k=1536]    (9633792 f)
#define WS_WTB  19669952L     // Wtb bf16 [oc=768][k=1536]      (589824 f)
#define WS_WOB  20259776L     // Wob bf16 [oc=32][k=1536]        (24576 f)
#define WS_W1B  20284352L     // W1b bf16 [ks=2][oc=96][kl=32]    (3072 f)

__device__ __forceinline__ unsigned short f2bf(float f) {
    unsigned int u = __builtin_bit_cast(unsigned int, f);
    u += 0x7fffu + ((u >> 16) & 1u);
    return (unsigned short)(u >> 16);
}
__device__ __forceinline__ float bf2f(unsigned short u) {
    unsigned int t = ((unsigned int)u) << 16;
    return __builtin_bit_cast(float, t);
}

typedef __attribute__((ext_vector_type(4))) unsigned short ushort4v;
typedef __attribute__((ext_vector_type(8))) unsigned short ushort8v;
typedef __attribute__((ext_vector_type(8))) short bf16x8;
typedef __attribute__((ext_vector_type(4))) float floatx4;

// ---------------------------------------------------------------------------
// K0: weight prep, transpose-via-LDS for coalescing.
// ---------------------------------------------------------------------------
__global__ __launch_bounds__(256) void k0_prep(
    const float* __restrict__ stem_w, const float* __restrict__ stem_b,
    const float* __restrict__ bn1_g,  const float* __restrict__ bn1_b,
    const float* __restrict__ bn1_m,  const float* __restrict__ bn1_v,
    const float* __restrict__ off_w,  const float* __restrict__ dcn_w,
    const float* __restrict__ dcn_b,  const float* __restrict__ bn2_g,
    const float* __restrict__ bn2_b,  const float* __restrict__ bn2_m,
    const float* __restrict__ bn2_v,  float* __restrict__ ws)
{
    const int tid = threadIdx.x;
    const int blk = blockIdx.x;
    unsigned short* Wtb = (unsigned short*)(ws + WS_WTB);
    unsigned short* Wob = (unsigned short*)(ws + WS_WOB);
    unsigned short* W1b = (unsigned short*)(ws + WS_W1B);

    if (blk < 800) {
        __shared__ float row[1536];
        const int oc = (blk < 768) ? blk : blk - 768;
        const float* src = (blk < 768) ? (dcn_w + (long)oc * 1536)
                                       : (off_w + (long)oc * 1536);
        for (int i = tid; i < 1536; i += 256) row[i] = src[i];
        float sc = 1.f;
        if (blk < 768) sc = bn2_g[oc] * rsqrtf(bn2_v[oc] + EPS);
        __syncthreads();
        if (tid < 192) {
            int k0 = tid * 8;
            ushort8v o;
#pragma unroll
            for (int t = 0; t < 8; t++) {
                int k = k0 + t;
                int kk = k / 96, c = k % 96;      // k = kk*96 + c
                ((unsigned short*)&o)[t] = f2bf(row[c * 16 + kk] * sc);
            }
            unsigned short* dst = (blk < 768) ? (Wtb + (long)oc * 1536 + k0)
                                              : (Wob + (long)oc * 1536 + k0);
            *(ushort8v*)dst = o;
        }
    } else {
        for (int i = tid; i < 6144; i += 256) {
            int ks = i / 3072, rr = i % 3072;
            int oc = rr >> 5, kl = rr & 31;
            int k = ks * 32 + kl;
            W1b[i] = f2bf(k < 48 ? stem_w[oc * 48 + k] : 0.f);
        }
        if (tid < 96) {
            float s = bn1_g[tid] * rsqrtf(bn1_v[tid] + EPS);
            ws[WS_S1 + tid] = s;
            ws[WS_T1 + tid] = stem_b[tid] * s + bn1_b[tid] - bn1_m[tid] * s;
        }
        for (int i = tid; i < 768; i += 256) {
            float inv2 = bn2_g[i] * rsqrtf(bn2_v[i] + EPS);
            ws[WS_T2 + i] = dcn_b[i] * inv2 + bn2_b[i] - bn2_m[i] * inv2;
        }
    }
}

// ---------------------------------------------------------------------------
// K1: stem conv as bf16 MFMA GEMM, coalesced staging + LDS-repacked stores.
// ---------------------------------------------------------------------------
__global__ __launch_bounds__(256) void k1_stem_mfma(
    const float* __restrict__ x, const unsigned short* __restrict__ W1b,
    const float* __restrict__ s1, const float* __restrict__ t1,
    unsigned short* __restrict__ h1)
{
    const int tid  = threadIdx.x;
    const int wave = tid >> 6, lane = tid & 63;
    const int m = lane & 15, quad = lane >> 4;
    const int p0 = blockIdx.x * 128;

    __shared__ unsigned short sm[14336];   // 28672 B
    unsigned short* sA = sm;               // [2][128][32]
    unsigned short* sB = sm + 8192;        // [2][96][32]

#pragma unroll
    for (int i = 0; i < 3; i++) {
        int inst = wave * 3 + i;
        const unsigned short* g = W1b + inst * 512 + lane * 8;
        __builtin_amdgcn_global_load_lds(
            (const __attribute__((address_space(1))) void*)g,
            (__attribute__((address_space(3))) void*)(sB + inst * 512), 16, 0, 0);
    }
    {
        int r = tid >> 1, off = 16 + (tid & 1) * 8;
        *(ushort8v*)&sA[4096 + r * 32 + off] = (ushort8v)0;
    }
#pragma unroll
    for (int i = 0; i < 6; i++) {
        int unit = i * 256 + tid;
        int r = unit & 127, s = unit >> 7;
        int ci = s >> 2, kh = s & 3;
        int p = p0 + r;
        int b = p / 3136, rem = p % 3136;
        int oy = rem / 56, ox = rem % 56;
        float4 v = *(const float4*)&x[((long)((b * 3 + ci) * 224 + oy * 4 + kh)) * 224 + ox * 4];
        ushort4v hv;
        hv.x = f2bf(v.x); hv.y = f2bf(v.y); hv.z = f2bf(v.z); hv.w = f2bf(v.w);
        int k0i = ci * 16 + kh * 4;
        *(ushort4v*)&sA[(k0i >> 5) * 4096 + r * 32 + (k0i & 31)] = hv;
    }
    __syncthreads();

    bf16x8 bfv[6][2], af[2][2];
#pragma unroll
    for (int j = 0; j < 6; j++)
#pragma unroll
        for (int ks = 0; ks < 2; ks++)
            bfv[j][ks] = *(const bf16x8*)&sB[ks * 3072 + (j * 16 + m) * 32 + quad * 8];
#pragma unroll
    for (int rt = 0; rt < 2; rt++)
#pragma unroll
        for (int ks = 0; ks < 2; ks++)
            af[rt][ks] = *(const bf16x8*)&sA[ks * 4096 + (wave * 32 + rt * 16 + m) * 32 + quad * 8];

    floatx4 acc[2][6];
#pragma unroll
    for (int rt = 0; rt < 2; rt++)
#pragma unroll
        for (int j = 0; j < 6; j++) {
            floatx4 a = (floatx4)0.f;
            a = __builtin_amdgcn_mfma_f32_16x16x32_bf16(af[rt][0], bfv[j][0], a, 0, 0, 0);
            a = __builtin_amdgcn_mfma_f32_16x16x32_bf16(af[rt][1], bfv[j][1], a, 0, 0, 0);
            acc[rt][j] = a;
        }

    __syncthreads();
#pragma unroll
    for (int j = 0; j < 6; j++) {
        int c = j * 16 + m;
        float sc = s1[c], bi = t1[c];
#pragma unroll
        for (int rt = 0; rt < 2; rt++)
#pragma unroll
            for (int r = 0; r < 4; r++) {
                int row = wave * 32 + rt * 16 + quad * 4 + r;
                float v = acc[rt][j][r] * sc + bi;
                v = v >= 0.f ? v : SLOPE * v;
                sm[row * 96 + c] = f2bf(v);
            }
    }
    __syncthreads();
#pragma unroll
    for (int i = 0; i < 6; i++) {
        int idx = (i * 256 + tid) * 8;
        *(ushort8v*)&h1[(long)p0 * 96 + idx] = *(const ushort8v*)&sm[idx];
    }
}

// ---------------------------------------------------------------------------
// K2: offset conv, K-split x4 across blocks + dbuf prefetch + atomic reduce.
// Block bx: nt = bx%98, ks = bx/98 handles k in [ks*384, ks*384+384).
// off must be memset to 0 beforehand; ks==0 partial adds off_b.
// ---------------------------------------------------------------------------
__global__ __launch_bounds__(256) void k2_mfma(
    const unsigned short* __restrict__ h1,   // bf16 NHWC
    const unsigned short* __restrict__ Wob,  // [32][1536] bf16
    const float* __restrict__ off_b, float* __restrict__ off)
{
    const int tid  = threadIdx.x;
    const int wave = tid >> 6, lane = tid & 63;
    const int m = lane & 15, quad = lane >> 4;
    const int nt = blockIdx.x % 98, ks = blockIdx.x / 98;
    const int n0 = nt * 128;

    __shared__ unsigned short sA[2][4096];   // [buf][128*32]
    __shared__ unsigned short sB[2][1024];   // [buf][32*32]

    const int skoff = (lane & 3) * 8;
    int n_a = n0 + wave * 32 + (lane >> 2);
    int n_b = n_a + 16;
    int ba = n_a / 196, pa = n_a % 196;
    int bb = n_b / 196, pb = n_b % 196;
    long pixa = ((long)(ba * 56 + (pa / 14) * 4) * 56 + (pa % 14) * 4);
    long pixb = ((long)(bb * 56 + (pb / 14) * 4) * 56 + (pb % 14) * 4);

    const unsigned short* gB = Wob + (long)(wave * 16 + (lane >> 2)) * 1536 + ks * 384 + skoff;
    const int lofA0 = (wave * 32) * 32;
    const int lofA1 = (wave * 32 + 16) * 32;
    const int lofB  = (wave * 16) * 32;

    auto issue = [&](int buf, int kt) {
        int khw = ks * 4 + kt / 3;
        int c0  = (kt % 3) * 32;
        int kh  = khw >> 2, kw = khw & 3;
        long eoff = (long)(kh * 56 + kw) * 96 + c0 + skoff;
        __builtin_amdgcn_global_load_lds(
            (const __attribute__((address_space(1))) void*)(h1 + pixa * 96 + eoff),
            (__attribute__((address_space(3))) void*)&sA[buf][lofA0], 16, 0, 0);
        __builtin_amdgcn_global_load_lds(
            (const __attribute__((address_space(1))) void*)(h1 + pixb * 96 + eoff),
            (__attribute__((address_space(3))) void*)&sA[buf][lofA1], 16, 0, 0);
        if (wave < 2)
            __builtin_amdgcn_global_load_lds(
                (const __attribute__((address_space(1))) void*)(gB + kt * 32),
                (__attribute__((address_space(3))) void*)&sB[buf][lofB], 16, 0, 0);
    };

    floatx4 acc[2][2];
#pragma unroll
    for (int i = 0; i < 2; i++)
#pragma unroll
        for (int j = 0; j < 2; j++) acc[i][j] = (floatx4)0.f;

    issue(0, 0);
    for (int kt = 0; kt < 12; ++kt) {
        __syncthreads();                       // drains tile kt's loads
        if (kt < 11) issue((kt + 1) & 1, kt + 1);
        const unsigned short* bufA = sA[kt & 1];
        const unsigned short* bufB = sB[kt & 1];
        bf16x8 af[2], bfr[2];
#pragma unroll
        for (int i = 0; i < 2; i++)
            af[i] = *(const bf16x8*)&bufA[(wave * 32 + i * 16 + m) * 32 + quad * 8];
#pragma unroll
        for (int j = 0; j < 2; j++)
            bfr[j] = *(const bf16x8*)&bufB[(j * 16 + m) * 32 + quad * 8];
#pragma unroll
        for (int i = 0; i < 2; i++)
#pragma unroll
            for (int j = 0; j < 2; j++)
                acc[i][j] = __builtin_amdgcn_mfma_f32_16x16x32_bf16(
                    af[i], bfr[j], acc[i][j], 0, 0, 0);
    }

    float tb[2];
#pragma unroll
    for (int j = 0; j < 2; j++) tb[j] = (ks == 0) ? off_b[j * 16 + m] : 0.f;
#pragma unroll
    for (int i = 0; i < 2; i++)
#pragma unroll
        for (int r = 0; r < 4; r++) {
            long n = n0 + wave * 32 + i * 16 + quad * 4 + r;
#pragma unroll
            for (int j = 0; j < 2; j++)
                atomicAdd(&off[n * 32 + j * 16 + m], acc[i][j][r] + tb[j]);
        }
}

// ---------------------------------------------------------------------------
// K3: bilinear sampling from bf16 h1 -> S bf16 [n][k], k = kk*96 + c.
// ---------------------------------------------------------------------------
__global__ __launch_bounds__(384) void k3_sample(
    const unsigned short* __restrict__ h1, const float* __restrict__ off,
    unsigned short* __restrict__ S)
{
    const int p = blockIdx.x;     // 0..195
    const int b = blockIdx.y;     // 0..63
    const int y = p / 14, xo = p % 14;
    const int tid = threadIdx.x;
    const int c4 = tid % 24, kk = tid / 24;
    const int kh = kk >> 2, kw = kk & 3;

    const float* ob = off + ((long)(b * 196 + p)) * 32;
    float dy = ob[kk * 2];
    float dx = ob[kk * 2 + 1];

    float py = (float)(y * 4 + kh) + dy;
    float px = (float)(xo * 4 + kw) + dx;
    float y0f = floorf(py), x0f = floorf(px);
    float wy = py - y0f, wx = px - x0f;
    int y0 = (int)y0f, x0 = (int)x0f;
    int y1 = y0 + 1,  x1 = x0 + 1;

    float my0 = (y0 >= 0 && y0 < 56) ? 1.f : 0.f;
    float my1 = (y1 >= 0 && y1 < 56) ? 1.f : 0.f;
    float mx0 = (x0 >= 0 && x0 < 56) ? 1.f : 0.f;
    float mx1 = (x1 >= 0 && x1 < 56) ? 1.f : 0.f;
    int y0c = min(max(y0, 0), 55), y1c = min(max(y1, 0), 55);
    int x0c = min(max(x0, 0), 55), x1c = min(max(x1, 0), 55);

    const unsigned short* hb = h1 + (long)b * 56 * 56 * 96 + c4 * 4;
    ushort4v v00 = *(const ushort4v*)&hb[(y0c * 56 + x0c) * 96];
    ushort4v v01 = *(const ushort4v*)&hb[(y0c * 56 + x1c) * 96];
    ushort4v v10 = *(const ushort4v*)&hb[(y1c * 56 + x0c) * 96];
    ushort4v v11 = *(const ushort4v*)&hb[(y1c * 56 + x1c) * 96];

    float w00 = my0 * mx0 * (1.f - wy) * (1.f - wx);
    float w01 = my0 * mx1 * (1.f - wy) * wx;
    float w10 = my1 * mx0 * wy * (1.f - wx);
    float w11 = my1 * mx1 * wy * wx;

    ushort4v rr;
#pragma unroll
    for (int c = 0; c < 4; c++) {
        float v = bf2f(((unsigned short*)&v00)[c]) * w00
                + bf2f(((unsigned short*)&v01)[c]) * w01
                + bf2f(((unsigned short*)&v10)[c]) * w10
                + bf2f(((unsigned short*)&v11)[c]) * w11;
        ((unsigned short*)&rr)[c] = f2bf(v);
    }

    long n = (long)b * 196 + p;
    *(ushort4v*)&S[n * 1536 + kk * 96 + c4 * 4] = rr;
}

// ---------------------------------------------------------------------------
// K4: bf16 MFMA GEMM  C[n][oc] = S[n][k] * Wtb[oc][k]^T  (N=12544,M=768,K=1536)
// 128n x 64oc tile -> 1176 blocks (4.6/CU). BK=32, 48 iters, single-barrier
// double-buffered prefetch (barrier -> issue kt+1 -> compute kt). XCD swizzle:
// each XCD gets 147 consecutive works (12 oc-tiles of an n-tile together).
// ---------------------------------------------------------------------------
__global__ __launch_bounds__(256) void k4_gemm_mfma(
    const unsigned short* __restrict__ S,    // [12544][1536] bf16
    const unsigned short* __restrict__ Wtb,  // [768][1536]  bf16 (B^T, scaled)
    const float* __restrict__ t2, float* __restrict__ out)
{
    const int tid  = threadIdx.x;
    const int wave = tid >> 6, lane = tid & 63;

    // swizzle: 1176 works = 8 XCDs x 147 consecutive works
    int lid = blockIdx.x;
    int work = (lid & 7) * 147 + (lid >> 3);
    const int n0  = (work / 12) * 128;
    const int oc0 = (work % 12) * 64;

    const int wr = wave >> 1, wc = wave & 1;
    const int m = lane & 15, quad = lane >> 4;

    __shared__ unsigned short sA[2][4096];   // [buf][128*32]
    __shared__ unsigned short sB[2][2048];   // [buf][64*32]

    const int skoff = (lane & 3) * 8;
    const unsigned short* gA0 = S + (long)(n0 + wave * 32 + (lane >> 2)) * 1536 + skoff;
    const unsigned short* gA1 = gA0 + 16L * 1536;
    const unsigned short* gB  = Wtb + (long)(oc0 + wave * 16 + (lane >> 2)) * 1536 + skoff;
    const int lofA0 = (wave * 32) * 32;
    const int lofA1 = (wave * 32 + 16) * 32;
    const int lofB  = (wave * 16) * 32;

    auto issue = [&](int buf) {
        __builtin_amdgcn_global_load_lds(
            (const __attribute__((address_space(1))) void*)gA0,
            (__attribute__((address_space(3))) void*)&sA[buf][lofA0], 16, 0, 0);
        __builtin_amdgcn_global_load_lds(
            (const __attribute__((address_space(1))) void*)gA1,
            (__attribute__((address_space(3))) void*)&sA[buf][lofA1], 16, 0, 0);
        __builtin_amdgcn_global_load_lds(
            (const __attribute__((address_space(1))) void*)gB,
            (__attribute__((address_space(3))) void*)&sB[buf][lofB], 16, 0, 0);
        gA0 += 32; gA1 += 32; gB += 32;
    };

    floatx4 acc[4][2];
#pragma unroll
    for (int i = 0; i < 4; i++)
#pragma unroll
        for (int j = 0; j < 2; j++) acc[i][j] = (floatx4)0.f;

    issue(0);
    for (int kt = 0; kt < 48; ++kt) {
        __syncthreads();                     // drains tile kt's loads (vmcnt)
        if (kt < 47) issue((kt + 1) & 1);    // prefetch flies during compute
        const unsigned short* bufA = sA[kt & 1];
        const unsigned short* bufB = sB[kt & 1];
        bf16x8 af[4], bf[2];
#pragma unroll
        for (int i = 0; i < 4; i++)
            af[i] = *(const bf16x8*)&bufA[(wr * 64 + i * 16 + m) * 32 + quad * 8];
#pragma unroll
        for (int j = 0; j < 2; j++)
            bf[j] = *(const bf16x8*)&bufB[(wc * 32 + j * 16 + m) * 32 + quad * 8];
#pragma unroll
        for (int i = 0; i < 4; i++)
#pragma unroll
            for (int j = 0; j < 2; j++)
                acc[i][j] = __builtin_amdgcn_mfma_f32_16x16x32_bf16(
                    af[i], bf[j], acc[i][j], 0, 0, 0);
    }

    float tb[2];
#pragma unroll
    for (int j = 0; j < 2; j++) tb[j] = t2[oc0 + wc * 32 + j * 16 + m];
#pragma unroll
    for (int i = 0; i < 4; i++) {
#pragma unroll
        for (int r = 0; r < 4; r++) {
            long n = n0 + wr * 64 + i * 16 + quad * 4 + r;
            float* orow = out + n * 768 + oc0 + wc * 32 + m;
#pragma unroll
            for (int j = 0; j < 2; j++) {
                float v = acc[i][j][r] + tb[j];
                orow[j * 16] = v >= 0.f ? v : SLOPE * v;
            }
        }
    }
}

// ---------------------------------------------------------------------------
extern "C" void kernel_launch(void* const* d_in, const int* in_sizes, int n_in,
                              void* d_out, int out_size, void* d_ws, size_t ws_size,
                              hipStream_t stream)
{
    const float* x      = (const float*)d_in[0];
    const float* stem_w = (const float*)d_in[1];
    const float* stem_b = (const float*)d_in[2];
    const float* bn1_g  = (const float*)d_in[3];
    const float* bn1_b  = (const float*)d_in[4];
    const float* bn1_m  = (const float*)d_in[5];
    const float* bn1_v  = (const float*)d_in[6];
    const float* off_w  = (const float*)d_in[7];
    const float* off_b  = (const float*)d_in[8];
    const float* dcn_w  = (const float*)d_in[9];
    const float* dcn_b  = (const float*)d_in[10];
    const float* bn2_g  = (const float*)d_in[11];
    const float* bn2_b  = (const float*)d_in[12];
    const float* bn2_m  = (const float*)d_in[13];
    const float* bn2_v  = (const float*)d_in[14];

    float* ws  = (float*)d_ws;        // needs 81.2 MB
    float* out = (float*)d_out;

    unsigned short* h1  = (unsigned short*)(ws + WS_H1B);
    float* off = ws + WS_OFF;
    float* s1  = ws + WS_S1;
    float* t1  = ws + WS_T1;
    float* t2  = ws + WS_T2;
    unsigned short* Sb  = (unsigned short*)(ws + WS_SB);
    unsigned short* Wtb = (unsigned short*)(ws + WS_WTB);
    unsigned short* Wob = (unsigned short*)(ws + WS_WOB);
    unsigned short* W1b = (unsigned short*)(ws + WS_W1B);

    k0_prep<<<801, 256, 0, stream>>>(stem_w, stem_b, bn1_g, bn1_b, bn1_m, bn1_v,
                                     off_w, dcn_w, dcn_b, bn2_g, bn2_b, bn2_m,
                                     bn2_v, ws);
    // zero the atomic-accumulated offset buffer (re-poisoned 0xAA each launch)
    hipMemsetAsync(off, 0, 401408 * sizeof(float), stream);
    k1_stem_mfma<<<1568, 256, 0, stream>>>(x, W1b, s1, t1, h1);
    k2_mfma<<<392, 256, 0, stream>>>(h1, Wob, off_b, off);
    k3_sample<<<dim3(196, 64), 384, 0, stream>>>(h1, off, Sb);
    k4_gemm_mfma<<<1176, 256, 0, stream>>>(Sb, Wtb, t2, out);
}